// Round 7
// baseline (269.644 us; speedup 1.0000x reference)
//
#include <hip/hip_runtime.h>
#include <cfloat>
#include <cmath>

#define VOCAB 8192
#define MTOT 16384
#define CDIM 256
#define KSPLIT 8
#define TAU 0.1f
#define IDX_INF 0x7fffffff

typedef __attribute__((ext_vector_type(8))) short bf16x8;
typedef __attribute__((ext_vector_type(4))) float f32x4;

#define AS1 __attribute__((address_space(1)))
#define AS3 __attribute__((address_space(3)))

__device__ __forceinline__ void gl_lds16(const void* g, void* l) {
  __builtin_amdgcn_global_load_lds((const AS1 unsigned int*)g,
                                   (AS3 unsigned int*)l, 16, 0, 0);
}

__device__ inline ushort f2bf(float f) {
  unsigned u = __float_as_uint(f);
  unsigned r = (u + 0x7fffu + ((u >> 16) & 1u)) >> 16;
  return (ushort)r;
}

// merge other top-2 (ob,oi,os,osi) into mine (b,i,s,si); order by (value, index)
__device__ inline void top2_merge(float& b, int& i, float& s, int& si,
                                  float ob, int oi, float os, int osi) {
  if (ob < b || (ob == b && oi < i)) {
    if (b < os || (b == os && i < osi)) { s = b; si = i; }
    else { s = os; si = osi; }
    b = ob; i = oi;
  } else {
    if (ob < s || (ob == s && oi < si)) { s = ob; si = oi; }
  }
}

// ---------------- enorm: ||e_k||^2 fp32 + exact fp64 ----------------
__global__ void vq_enorm_kernel(const float* __restrict__ emb,
                                float* __restrict__ enorm,
                                double* __restrict__ enormd) {
  __shared__ double sd[4][64];
  int tid = threadIdx.x;
  int kk = tid & 63, cg = tid >> 6;
  int k = blockIdx.x * 64 + kk;
  double s = 0.0;
  for (int c = cg * 64; c < cg * 64 + 64; ++c) {
    float v = emb[(size_t)c * VOCAB + k];
    s += (double)v * (double)v;
  }
  sd[cg][kk] = s;
  __syncthreads();
  if (cg == 0) {
    double t = sd[0][kk] + sd[1][kk] + sd[2][kk] + sd[3][kk];
    enorm[k] = (float)t;
    enormd[k] = t;
  }
}

// ---------------- transpose emb [C][K] -> embT [K][C] fp32 ----------------
__global__ void vq_prep_embT_kernel(const float* __restrict__ emb,
                                    float* __restrict__ embT) {
  __shared__ float t[32][33];
  int bc = blockIdx.x & 7;    // C/32 = 8
  int bk = blockIdx.x >> 3;   // K/32 = 256
  int lx = threadIdx.x & 31, lyq = threadIdx.x >> 5;
#pragma unroll
  for (int yy = 0; yy < 4; ++yy) {
    int y = lyq * 4 + yy;
    t[y][lx] = emb[(size_t)(bc * 32 + y) * VOCAB + bk * 32 + lx];
  }
  __syncthreads();
#pragma unroll
  for (int yy = 0; yy < 4; ++yy) {
    int y = lyq * 4 + yy;
    embT[(size_t)(bk * 32 + y) * CDIM + bc * 32 + lx] = t[lx][y];
  }
}

// ---------------- pack -2x -> bf16 slot-swizzled strips ----------------
// granule u: slot=u&3; row=(u>>2)&63; cc=(u>>8)&7; rb=u>>11
// content: -2*x[rb*64+row][cc*32 + ((slot^(row&3))<<3) .. +8]
__global__ void vq_pack_x_kernel(const float* __restrict__ x,
                                 ushort* __restrict__ xb) {
  int u = blockIdx.x * 256 + threadIdx.x;
  int slot = u & 3, row = (u >> 2) & 63, cc = (u >> 8) & 7, rb = u >> 11;
  int dims = cc * 32 + ((slot ^ (row & 3)) << 3);
  const float* src = x + (size_t)(rb * 64 + row) * CDIM + dims;
  float4 v0 = *(const float4*)src;
  float4 v1 = *(const float4*)(src + 4);
  float a[8] = {v0.x, v0.y, v0.z, v0.w, v1.x, v1.y, v1.z, v1.w};
  bf16x8 h;
#pragma unroll
  for (int j = 0; j < 8; ++j) h[j] = (short)f2bf(-2.0f * a[j]);
  *(bf16x8*)(xb + (size_t)u * 8) = h;
}

// ---------------- pack embT -> bf16 slot-swizzled wave-chunks ----------------
// granule u: slot=u&3; code=(u>>2)&63; cc=(u>>8)&7; cg=(u>>11)&3; wc=(u>>13)&3; sp=u>>15
__global__ void vq_pack_e_kernel(const float* __restrict__ embT,
                                 ushort* __restrict__ eb) {
  int u = blockIdx.x * 256 + threadIdx.x;
  int slot = u & 3, code = (u >> 2) & 63, cc = (u >> 8) & 7;
  int cg = (u >> 11) & 3, wcp = (u >> 13) & 3, sp = u >> 15;
  int cglob = sp * 1024 + wcp * 256 + cg * 64 + code;
  int dims = cc * 32 + ((slot ^ (code & 3)) << 3);
  const float* src = embT + (size_t)cglob * CDIM + dims;
  float4 v0 = *(const float4*)src;
  float4 v1 = *(const float4*)(src + 4);
  float a[8] = {v0.x, v0.y, v0.z, v0.w, v1.x, v1.y, v1.z, v1.w};
  bf16x8 h;
#pragma unroll
  for (int j = 0; j < 8; ++j) h[j] = (short)f2bf(a[j]);
  *(bf16x8*)(eb + (size_t)u * 8) = h;
}

// ---------------- bf16 MFMA distance: barrier-free per-wave pipeline ----------------
// block = 4 waves (1x4), 64 rows x 1024 codes (split sp). A (32KB) shared,
// read-only after prologue. Each wave streams its own 4KB B-chunks with
// counted vmcnt(4) double-buffering. No __syncthreads in the main loop.
__global__ __launch_bounds__(256, 2) void vq_dist_kernel(
    const ushort* __restrict__ xb, const ushort* __restrict__ eb,
    const float* __restrict__ enorm,
    float4* __restrict__ pkd, int4* __restrict__ pki) {
  __shared__ ushort Abuf[16384];          // 32 KB [cc8][row64][slot4]
  __shared__ ushort Bbuf[4][2][2048];     // per-wave 2 x 4KB
  __shared__ float msd[2][4][64];
  __shared__ int msi[2][4][64];

  const int tid = threadIdx.x;
  const int lane = tid & 63, wc = tid >> 6;
  const int l15 = lane & 15, lg = lane >> 4;
  const int rb = blockIdx.x >> 3, sp = blockIdx.x & 7;
  const int m0 = rb * 64;
  const int nbase = sp * 1024 + wc * 256;

  const ushort* xs = xb + (size_t)rb * 16384;
  const ushort* ebw = eb + (size_t)(sp * 4 + wc) * 65536;

  // prologue: stage A strip (8 insts/wave) + own B chunk 0 (4 insts)
#pragma unroll
  for (int i = 0; i < 8; ++i)
    gl_lds16(xs + (wc * 8 + i) * 512 + lane * 8, &Abuf[(wc * 8 + i) * 512]);
#pragma unroll
  for (int i = 0; i < 4; ++i)
    gl_lds16(ebw + i * 512 + lane * 8, &Bbuf[wc][0][i * 512]);

  // prefetch enorm values for all 16 code-columns this lane will own
  float en[16];
#pragma unroll
  for (int cg = 0; cg < 4; ++cg)
#pragma unroll
    for (int nf = 0; nf < 4; ++nf)
      en[cg * 4 + nf] = enorm[nbase + cg * 64 + nf * 16 + l15];

  __syncthreads();   // drains prologue staging (compiler emits vmcnt(0)); A visible

  // hoisted LDS byte offsets (slot-swizzle: slot = lg ^ (idx&3))
  uint offA[4], offB[4];
#pragma unroll
  for (int mf = 0; mf < 4; ++mf) {
    int row = mf * 16 + l15;
    offA[mf] = row * 64 + ((lg ^ (row & 3)) << 4);
  }
#pragma unroll
  for (int nf = 0; nf < 4; ++nf) {
    int code = nf * 16 + l15;
    offB[nf] = code * 64 + ((lg ^ (code & 3)) << 4);
  }
  const char* Bbase = (const char*)&Bbuf[wc][0][0];

  float bv[16];
  int bi[16];
#pragma unroll
  for (int s = 0; s < 16; ++s) { bv[s] = FLT_MAX; bi[s] = 0; }

#pragma unroll
  for (int cg = 0; cg < 4; ++cg) {
    f32x4 acc[4][4];
#pragma unroll
    for (int mf = 0; mf < 4; ++mf)
#pragma unroll
      for (int nf = 0; nf < 4; ++nf) {
        float e = en[cg * 4 + nf];
        acc[mf][nf] = (f32x4){e, e, e, e};
      }
#pragma unroll
    for (int cc = 0; cc < 8; ++cc) {
      const int t = cg * 8 + cc;
      // previous chunk's ds_reads fully consumed before overwriting its buffer
      asm volatile("s_waitcnt lgkmcnt(0)" ::: "memory");
      if (t < 31) {
        const ushort* src = ebw + (size_t)(t + 1) * 2048;
        char* dst = (char*)&Bbuf[wc][(t + 1) & 1][0];
#pragma unroll
        for (int i = 0; i < 4; ++i)
          gl_lds16(src + i * 512 + lane * 8, dst + i * 1024);
        asm volatile("s_waitcnt vmcnt(4)" ::: "memory");  // chunk t resident
      } else {
        asm volatile("s_waitcnt vmcnt(0)" ::: "memory");
      }
      __builtin_amdgcn_sched_barrier(0);
      const char* Ab = (const char*)Abuf + cc * 4096;
      const char* Bb = Bbase + (cc & 1) * 4096;
      bf16x8 af[4], bfr[4];
#pragma unroll
      for (int mf = 0; mf < 4; ++mf) af[mf] = *(const bf16x8*)(Ab + offA[mf]);
#pragma unroll
      for (int nf = 0; nf < 4; ++nf) bfr[nf] = *(const bf16x8*)(Bb + offB[nf]);
#pragma unroll
      for (int mf = 0; mf < 4; ++mf)
#pragma unroll
        for (int nf = 0; nf < 4; ++nf)
          acc[mf][nf] = __builtin_amdgcn_mfma_f32_16x16x32_bf16(af[mf], bfr[nf], acc[mf][nf], 0, 0, 0);
    }
    // fold this code-group's distances into per-stream minima (strict < = first occurrence)
#pragma unroll
    for (int nf = 0; nf < 4; ++nf) {
      int n = nbase + cg * 64 + nf * 16 + l15;
#pragma unroll
      for (int mf = 0; mf < 4; ++mf)
#pragma unroll
        for (int r = 0; r < 4; ++r) {
          float d = acc[mf][nf][r];
          int s = mf * 4 + r;
          if (d < bv[s]) { bv[s] = d; bi[s] = n; }
        }
    }
  }

  // per-row top-2 across the 16 column-lanes (in-register, no LDS)
#pragma unroll
  for (int mf = 0; mf < 4; ++mf)
#pragma unroll
    for (int r = 0; r < 4; ++r) {
      int s = mf * 4 + r;
      float b = bv[s], sec = FLT_MAX;
      int i = bi[s], si = IDX_INF;
#pragma unroll
      for (int m = 1; m < 16; m <<= 1) {
        float ob = __shfl_xor(b, m, 64);
        float os = __shfl_xor(sec, m, 64);
        int oi = __shfl_xor(i, m, 64);
        int osi = __shfl_xor(si, m, 64);
        top2_merge(b, i, sec, si, ob, oi, os, osi);
      }
      if (l15 == 0) {
        int row = mf * 16 + lg * 4 + r;
        msd[0][wc][row] = b; msi[0][wc][row] = i;
        msd[1][wc][row] = sec; msi[1][wc][row] = si;
      }
    }
  __syncthreads();
  if (tid < 64) {
    float d[4] = {FLT_MAX, FLT_MAX, FLT_MAX, FLT_MAX};
    int ix[4] = {IDX_INF, IDX_INF, IDX_INF, IDX_INF};
#pragma unroll
    for (int w = 0; w < 4; ++w)
#pragma unroll
      for (int e = 0; e < 2; ++e) {
        float a = msd[e][w][tid];
        int ai = msi[e][w][tid];
#pragma unroll
        for (int q = 0; q < 4; ++q) {
          bool lt = (a < d[q]) || (a == d[q] && ai < ix[q]);
          float td = lt ? d[q] : a;
          int ti = lt ? ix[q] : ai;
          d[q] = lt ? a : d[q];
          ix[q] = lt ? ai : ix[q];
          a = td; ai = ti;
        }
      }
    pkd[(size_t)sp * MTOT + m0 + tid] = make_float4(d[0], d[1], d[2], d[3]);
    pki[(size_t)sp * MTOT + m0 + tid] = make_int4(ix[0], ix[1], ix[2], ix[3]);
  }
}

// ---------------- merge 32 candidates + fp64 rescue + gather (1 wave / row) ----------------
__global__ void vq_gather_kernel(
    const float* __restrict__ x, const float* __restrict__ embT,
    const double* __restrict__ enormd,
    const float4* __restrict__ pkd, const int4* __restrict__ pki,
    float* __restrict__ out, int* __restrict__ counts, float* __restrict__ ssep) {
  const int wid = threadIdx.x >> 6, lane = threadIdx.x & 63;
  const int m = blockIdx.x * 4 + wid;

  const float4 xq = *(const float4*)(x + (size_t)m * CDIM + lane * 4);

  float bd = FLT_MAX, sd = FLT_MAX;
  int bidx = IDX_INF;
#pragma unroll
  for (int sp2 = 0; sp2 < KSPLIT; ++sp2) {
    float4 dv = pkd[(size_t)sp2 * MTOT + m];
    int4 iv = pki[(size_t)sp2 * MTOT + m];
    float ds[4] = {dv.x, dv.y, dv.z, dv.w};
    int is[4] = {iv.x, iv.y, iv.z, iv.w};
#pragma unroll
    for (int j = 0; j < 4; ++j) {
      float dj = ds[j];
      int ij = is[j];
      if (dj < bd || (dj == bd && ij < bidx)) { sd = bd; bd = dj; bidx = ij; }
      else sd = fminf(sd, dj);
    }
  }
  int best = bidx;
  if (sd - bd < TAU) {   // ambiguous: exact fp64 over all 32 candidates (wave-uniform)
    double bD = DBL_MAX;
    int bn = IDX_INF;
    for (int sp2 = 0; sp2 < KSPLIT; ++sp2) {
      int4 iv = pki[(size_t)sp2 * MTOT + m];
      int is[4] = {iv.x, iv.y, iv.z, iv.w};
#pragma unroll
      for (int j = 0; j < 4; ++j) {
        int cj = is[j];
        const float4 ev = *(const float4*)(embT + (size_t)cj * CDIM + lane * 4);
        double p = (double)xq.x * ev.x + (double)xq.y * ev.y
                 + (double)xq.z * ev.z + (double)xq.w * ev.w;
#pragma unroll
        for (int off = 1; off < 64; off <<= 1) p += __shfl_xor(p, off, 64);
        double dj = enormd[cj] - 2.0 * p;
        if (dj < bD || (dj == bD && cj < bn)) { bD = dj; bn = cj; }
      }
    }
    best = bn;
  }
  const float4 ev = *(const float4*)(embT + (size_t)best * CDIM + lane * 4);
  *(float4*)(out + (size_t)m * CDIM + lane * 4) = ev;
  float dx = ev.x - xq.x, dy = ev.y - xq.y, dz = ev.z - xq.z, dw = ev.w - xq.w;
  float v = dx * dx + dy * dy + dz * dz + dw * dw;
#pragma unroll
  for (int off = 32; off > 0; off >>= 1) v += __shfl_down(v, off, 64);
  if (lane == 0) {
    ssep[m] = v;
    atomicAdd(&counts[best], 1);
  }
}

// ---------------- loss + perplexity, two-stage deterministic ----------------
__global__ void vq_final1_kernel(const float* __restrict__ ssep,
                                 const int* __restrict__ counts,
                                 double* __restrict__ part) {
  __shared__ double red[256];
  const int tid = threadIdx.x, b = blockIdx.x;
  red[tid] = (double)ssep[b * 256 + tid];
  __syncthreads();
  for (int off = 128; off > 0; off >>= 1) {
    if (tid < off) red[tid] += red[tid + off];
    __syncthreads();
  }
  if (tid == 0) part[b] = red[0];
  __syncthreads();
  double e = 0.0;
  if (tid < 128) {
    double p = (double)counts[b * 128 + tid] / (double)MTOT;
    e = p * log(p + 1e-10);
  }
  red[tid] = e;
  __syncthreads();
  for (int off = 128; off > 0; off >>= 1) {
    if (tid < off) red[tid] += red[tid + off];
    __syncthreads();
  }
  if (tid == 0) part[64 + b] = red[0];
}

__global__ void vq_final2_kernel(const double* __restrict__ part,
                                 float* __restrict__ out) {
  const int lane = threadIdx.x;   // 64 threads
  double s = part[lane], e = part[64 + lane];
#pragma unroll
  for (int off = 32; off > 0; off >>= 1) {
    s += __shfl_down(s, off, 64);
    e += __shfl_down(e, off, 64);
  }
  if (lane == 0) {
    out[(size_t)MTOT * CDIM] = (float)(1.25 * s / (double)((size_t)MTOT * CDIM));
    out[(size_t)MTOT * CDIM + 1] = (float)exp(-e);
  }
}

extern "C" void kernel_launch(void* const* d_in, const int* in_sizes, int n_in,
                              void* d_out, int out_size, void* d_ws, size_t ws_size,
                              hipStream_t stream) {
  const float* x = (const float*)d_in[0];
  const float* emb = (const float*)d_in[1];
  float* out = (float*)d_out;
  char* ws = (char*)d_ws;

  // workspace layout (bytes)
  double* enormd = (double*)(ws);                 //        0: 65536
  float* enorm   = (float*)(ws + 65536);          //    65536: 32768
  float4* pkd    = (float4*)(ws + 98304);         //    98304: 2097152
  int4* pki      = (int4*)(ws + 2195456);         //  2195456: 2097152
  int* counts    = (int*)(ws + 4292608);          //  4292608: 32768
  float* ssep    = (float*)(ws + 4325376);        //  4325376: 65536
  double* part   = (double*)(ws + 4390912);       //  4390912: 1024
  float* embT    = (float*)(ws + 4391936);        //  4391936: 8388608
  ushort* xb     = (ushort*)(ws + 12780544);      // 12780544: 8388608
  ushort* eb     = (ushort*)(ws + 21169152);      // 21169152: 4194304
  // total 25363456 bytes (< 35 MB proven available in rounds 1-6)

  hipMemsetAsync(counts, 0, VOCAB * sizeof(int), stream);
  vq_enorm_kernel<<<VOCAB / 64, 256, 0, stream>>>(emb, enorm, enormd);
  vq_prep_embT_kernel<<<(VOCAB / 32) * (CDIM / 32), 256, 0, stream>>>(emb, embT);
  vq_pack_e_kernel<<<(VOCAB * CDIM / 8) / 256, 256, 0, stream>>>(embT, eb);
  vq_pack_x_kernel<<<(MTOT * CDIM / 8) / 256, 256, 0, stream>>>(x, xb);
  vq_dist_kernel<<<(MTOT / 64) * KSPLIT, 256, 0, stream>>>(xb, eb, enorm, pkd, pki);
  vq_gather_kernel<<<MTOT / 4, 256, 0, stream>>>(x, embT, enormd, pkd, pki,
                                                 out, counts, ssep);
  vq_final1_kernel<<<64, 256, 0, stream>>>(ssep, counts, part);
  vq_final2_kernel<<<1, 64, 0, stream>>>(part, out);
}